// Round 3
// baseline (310.457 us; speedup 1.0000x reference)
//
#include <hip/hip_runtime.h>
#include <cmath>
#include <cstdint>
#include <cstring>

// ---------------------------------------------------------------------------
// eps = jax.random.normal(jax.random.key(42), (4,4)) reproduced on HOST.
// Partitionable threefry stream (verified PASS in round 2): counter (0, e),
// XOR-fold the 2x32 outputs; bits>>9|0x3f800000 -> [1,2); affine to
// [nextafter(-1,0), 1); sqrt(2)*erfinv.
// ---------------------------------------------------------------------------

static inline uint32_t rotl32(uint32_t v, int r) { return (v << r) | (v >> (32 - r)); }

static void threefry2x32_42(uint32_t x0, uint32_t x1, uint32_t& o0, uint32_t& o1) {
    const uint32_t k0 = 0u, k1 = 42u;
    const uint32_t ks[3] = { k0, k1, k0 ^ k1 ^ 0x1BD11BDAu };
    static const int R[8] = { 13, 15, 26, 6, 17, 29, 16, 24 };
    x0 += ks[0];
    x1 += ks[1];
    for (int g = 1; g <= 5; ++g) {
        const int* rr = &R[((g - 1) & 1) * 4];
        for (int j = 0; j < 4; ++j) {
            x0 += x1;
            x1 = rotl32(x1, rr[j]);
            x1 ^= x0;
        }
        x0 += ks[g % 3];
        x1 += ks[(g + 1) % 3] + (uint32_t)g;
    }
    o0 = x0;
    o1 = x1;
}

static double erfinv_d(double x) {
    float xf = (float)x;
    float w = -logf((1.0f - xf) * (1.0f + xf));
    float p;
    if (w < 5.0f) {
        w -= 2.5f;
        p = 2.81022636e-08f;
        p = fmaf(p, w, 3.43273939e-07f);
        p = fmaf(p, w, -3.5233877e-06f);
        p = fmaf(p, w, -4.39150654e-06f);
        p = fmaf(p, w, 0.00021858087f);
        p = fmaf(p, w, -0.00125372503f);
        p = fmaf(p, w, -0.00417768164f);
        p = fmaf(p, w, 0.246640727f);
        p = fmaf(p, w, 1.50140941f);
    } else {
        w = sqrtf(w) - 3.0f;
        p = -0.000200214257f;
        p = fmaf(p, w, 0.000100950558f);
        p = fmaf(p, w, 0.00134934322f);
        p = fmaf(p, w, -0.00367342844f);
        p = fmaf(p, w, 0.00573950773f);
        p = fmaf(p, w, -0.0076224613f);
        p = fmaf(p, w, 0.00943887047f);
        p = fmaf(p, w, 1.00167406f);
        p = fmaf(p, w, 2.83297682f);
    }
    double y = (double)(p * xf);
    const double c = 1.1283791670955126;
    for (int it = 0; it < 3; ++it) {
        double err = erf(y) - x;
        y -= err / (c * exp(-y * y));
    }
    return y;
}

struct EpsT { float e[16]; };

static void compute_eps(float* e) {
    const float lo = -0.99999994f;
    for (int i = 0; i < 16; ++i) {
        uint32_t a, b;
        threefry2x32_42(0u, (uint32_t)i, a, b);
        uint32_t bits = a ^ b;
        uint32_t fb = (bits >> 9) | 0x3f800000u;
        float f;
        memcpy(&f, &fb, 4);
        float u = f - 1.0f;
        float v = u * 2.0f + lo;
        if (v < lo) v = lo;
        e[i] = (float)(sqrt(2.0) * erfinv_d((double)v));
    }
}

// ---------------------------------------------------------------------------
// MFMA kernel. Transposed formulation so batch rows ride the N/col axis:
//   C/D layout (verified): col = lane&31 (= batch row), row = (r&3)+8*(r>>2)+4*half
//   A layout (extrapolated from verified 16x16x32): A[m=lane&31][k=half*8+j]
//   B layout:                                       B[k=half*8+j][n=lane&31]
// Chain: C1 = W1m_i(A) x Z^T(B); relu; half-swap -> B-frag; C2 = W2^T x ...;
// relu; half-swap; C3 = W3^T(pad) x ...  -> lanes<32, regs 0-3 = out[row][4i+f].
// Mask folds into W1 A-frag (k&3 == j&3, lane-uniform). Biases init the accs.
// One wave per 32-row tile, grid-stride, z prefetch. No LDS, no barriers.
// ---------------------------------------------------------------------------

typedef _Float16 half8 __attribute__((ext_vector_type(8)));
typedef float floatx16 __attribute__((ext_vector_type(16)));

__global__ __launch_bounds__(256) void scm_mfma(
    const float* __restrict__ z,
    const float* __restrict__ W1, const float* __restrict__ b1,
    const float* __restrict__ W2, const float* __restrict__ b2,
    const float* __restrict__ W3, const float* __restrict__ b3,
    const int* __restrict__ mask,
    float* __restrict__ out, EpsT ep, int B)
{
    const int lane = threadIdx.x & 63;
    const int hv   = lane >> 5;          // half of the wave
    const int r32  = lane & 31;          // row-in-tile / m / n index
    const int wid  = blockIdx.x * (blockDim.x >> 6) + (threadIdx.x >> 6);
    const int nw   = gridDim.x * (blockDim.x >> 6);
    const int T    = B >> 5;             // 32-row tiles

    int mk[16];
#pragma unroll
    for (int t = 0; t < 16; ++t) mk[t] = mask[t];     // uniform -> s_load
    int cond[4];
#pragma unroll
    for (int i = 0; i < 4; ++i) cond[i] = mk[i] | mk[4 + i] | mk[8 + i] | mk[12 + i];
    const bool allc = cond[0] && cond[1] && cond[2] && cond[3];

    // ---- weight A-fragments (f16), built once per wave ----
    half8 w1m[4], w2f[2], w3f[2];
#pragma unroll
    for (int j = 0; j < 8; ++j) {
        const int k = hv * 8 + j;                     // k in [0,16)
        const float w = W1[k * 32 + r32];             // W1^T[m=r32][k]
#pragma unroll
        for (int i = 0; i < 4; ++i)                   // mask[f=k&3=j&3][i]
            w1m[i][j] = mk[(j & 3) * 4 + i] ? (_Float16)w : (_Float16)0.f;
    }
#pragma unroll
    for (int q = 0; q < 2; ++q)
#pragma unroll
        for (int j = 0; j < 8; ++j) {
            const int k = q * 16 + hv * 8 + j;        // k in [0,32)
            w2f[q][j] = (_Float16)W2[k * 32 + r32];   // W2^T[m=r32][k]
            w3f[q][j] = (r32 < 4) ? (_Float16)W3[k * 4 + r32] : (_Float16)0.f;
        }

    // ---- biases in C/D layout: acc-init ----
    floatx16 b1v, b2v;
#pragma unroll
    for (int r = 0; r < 16; ++r) {
        const int h = (r & 3) + 8 * (r >> 2) + 4 * hv;
        b1v[r] = b1[h];
        b2v[r] = b2[h];
    }
    float c3i[4][4];                                  // b3[f] + eps[i][f] (uniform)
#pragma unroll
    for (int i = 0; i < 4; ++i)
#pragma unroll
        for (int f = 0; f < 4; ++f) c3i[i][f] = b3[f] + ep.e[i * 4 + f];

    // ---- grid-stride tile loop with z prefetch ----
    int t = wid;
    float4 za = make_float4(0.f, 0.f, 0.f, 0.f), zb = za;
    if (t < T) {
        const float4* p = reinterpret_cast<const float4*>(z + ((size_t)t * 32 + r32) * 16) + hv * 2;
        za = p[0]; zb = p[1];                         // z[row][hv*8 .. hv*8+7]
    }
    while (t < T) {
        const int tn = t + nw;
        float4 na = make_float4(0.f, 0.f, 0.f, 0.f), nb = na;
        if (tn < T) {
            const float4* p = reinterpret_cast<const float4*>(z + ((size_t)tn * 32 + r32) * 16) + hv * 2;
            na = p[0]; nb = p[1];
        }

        float zf[8] = { za.x, za.y, za.z, za.w, zb.x, zb.y, zb.z, zb.w };
        half8 bz;                                     // Z^T B-frag (shared by all 4 cols)
#pragma unroll
        for (int j = 0; j < 8; ++j) bz[j] = (_Float16)zf[j];

        float zx[8] = { 0.f, 0.f, 0.f, 0.f, 0.f, 0.f, 0.f, 0.f };
        if (!allc) {                                  // exact f32 passthrough data
#pragma unroll
            for (int j = 0; j < 8; ++j) zx[j] = __shfl_xor(zf[j], 32);
        }

        float ov[16];                                 // out row (valid on lanes<32)
#pragma unroll
        for (int i = 0; i < 4; ++i) {
            if (cond[i]) {
                // L1: K=16, one MFMA
                floatx16 c1 = b1v;
                c1 = __builtin_amdgcn_mfma_f32_32x32x16_f16(w1m[i], bz, c1, 0, 0, 0);
                float v[16];
#pragma unroll
                for (int r = 0; r < 16; ++r) v[r] = fmaxf(c1[r], 0.f);
                // C/D -> B-frag half-swap (h 4-7 <-> 8-11, 20-23 <-> 24-27)
                float ra[4], rb[4];
#pragma unroll
                for (int q = 0; q < 4; ++q) ra[q] = __shfl_xor(hv ? v[q] : v[4 + q], 32);
#pragma unroll
                for (int q = 0; q < 4; ++q) rb[q] = __shfl_xor(hv ? v[8 + q] : v[12 + q], 32);
                half8 pa, pb;
#pragma unroll
                for (int j = 0; j < 8; ++j) {
                    float fa, fb;
                    if (j < 4) { fa = hv ? ra[j] : v[j];         fb = hv ? rb[j] : v[8 + j]; }
                    else       { fa = hv ? v[j] : ra[j - 4];     fb = hv ? v[8 + j] : rb[j - 4]; }
                    pa[j] = (_Float16)fa; pb[j] = (_Float16)fb;
                }
                // L2: K=32, two MFMAs
                floatx16 c2 = b2v;
                c2 = __builtin_amdgcn_mfma_f32_32x32x16_f16(w2f[0], pa, c2, 0, 0, 0);
                c2 = __builtin_amdgcn_mfma_f32_32x32x16_f16(w2f[1], pb, c2, 0, 0, 0);
#pragma unroll
                for (int r = 0; r < 16; ++r) v[r] = fmaxf(c2[r], 0.f);
#pragma unroll
                for (int q = 0; q < 4; ++q) ra[q] = __shfl_xor(hv ? v[q] : v[4 + q], 32);
#pragma unroll
                for (int q = 0; q < 4; ++q) rb[q] = __shfl_xor(hv ? v[8 + q] : v[12 + q], 32);
#pragma unroll
                for (int j = 0; j < 8; ++j) {
                    float fa, fb;
                    if (j < 4) { fa = hv ? ra[j] : v[j];         fb = hv ? rb[j] : v[8 + j]; }
                    else       { fa = hv ? v[j] : ra[j - 4];     fb = hv ? v[8 + j] : rb[j - 4]; }
                    pa[j] = (_Float16)fa; pb[j] = (_Float16)fb;
                }
                // L3: W3^T padded to 32 rows; valid f=0..3 on lanes<32 regs 0..3
                floatx16 c3;
#pragma unroll
                for (int r = 0; r < 16; ++r) c3[r] = (r < 4) ? c3i[i][r] : 0.f;
                c3 = __builtin_amdgcn_mfma_f32_32x32x16_f16(w3f[0], pa, c3, 0, 0, 0);
                c3 = __builtin_amdgcn_mfma_f32_32x32x16_f16(w3f[1], pb, c3, 0, 0, 0);
#pragma unroll
                for (int f = 0; f < 4; ++f) ov[i * 4 + f] = c3[f];
            } else {
                // exact passthrough: cols 0-1 local (zf), cols 2-3 from partner (zx)
#pragma unroll
                for (int f = 0; f < 4; ++f)
                    ov[i * 4 + f] = (i < 2) ? zf[i * 4 + f] : zx[(i - 2) * 4 + f];
            }
        }
        if (hv == 0) {
            float4* op = reinterpret_cast<float4*>(out + ((size_t)t * 32 + r32) * 16);
#pragma unroll
            for (int q = 0; q < 4; ++q)
                op[q] = make_float4(ov[4 * q], ov[4 * q + 1], ov[4 * q + 2], ov[4 * q + 3]);
        }
        t = tn; za = na; zb = nb;
    }
}

extern "C" void kernel_launch(void* const* d_in, const int* in_sizes, int n_in,
                              void* d_out, int out_size, void* d_ws, size_t ws_size,
                              hipStream_t stream) {
    const float* z  = (const float*)d_in[0];
    // d_in[1] = z_int (dead code in reference)
    const float* W1 = (const float*)d_in[2];
    const float* b1 = (const float*)d_in[3];
    const float* W2 = (const float*)d_in[4];
    const float* b2 = (const float*)d_in[5];
    const float* W3 = (const float*)d_in[6];
    const float* b3 = (const float*)d_in[7];
    const int* mask = (const int*)d_in[8];
    // d_in[9] = I (dead code in reference)
    float* out = (float*)d_out;

    const int B = in_sizes[0] / 16;

    EpsT ep;
    compute_eps(ep.e);   // pure host math, deterministic, capture-safe

    dim3 grid(2048), block(256);   // 8192 waves, grid-stride over B/32 tiles
    hipLaunchKernelGGL(scm_mfma, grid, block, 0, stream,
                       z, W1, b1, W2, b2, W3, b3, mask, out, ep, B);
}

// Round 4
// 210.911 us; speedup vs baseline: 1.4720x; 1.4720x over previous
//
#include <hip/hip_runtime.h>
#include <cmath>
#include <cstdint>
#include <cstring>

// ---------------------------------------------------------------------------
// eps = jax.random.normal(jax.random.key(42), (4,4)) reproduced on HOST.
// Partitionable threefry stream (verified PASS in rounds 2-3): counter (0,e),
// XOR-fold the 2x32 outputs; bits>>9|0x3f800000 -> [1,2); affine to
// [nextafter(-1,0), 1); sqrt(2)*erfinv.
// ---------------------------------------------------------------------------

static inline uint32_t rotl32(uint32_t v, int r) { return (v << r) | (v >> (32 - r)); }

static void threefry2x32_42(uint32_t x0, uint32_t x1, uint32_t& o0, uint32_t& o1) {
    const uint32_t k0 = 0u, k1 = 42u;
    const uint32_t ks[3] = { k0, k1, k0 ^ k1 ^ 0x1BD11BDAu };
    static const int R[8] = { 13, 15, 26, 6, 17, 29, 16, 24 };
    x0 += ks[0];
    x1 += ks[1];
    for (int g = 1; g <= 5; ++g) {
        const int* rr = &R[((g - 1) & 1) * 4];
        for (int j = 0; j < 4; ++j) {
            x0 += x1;
            x1 = rotl32(x1, rr[j]);
            x1 ^= x0;
        }
        x0 += ks[g % 3];
        x1 += ks[(g + 1) % 3] + (uint32_t)g;
    }
    o0 = x0;
    o1 = x1;
}

static double erfinv_d(double x) {
    float xf = (float)x;
    float w = -logf((1.0f - xf) * (1.0f + xf));
    float p;
    if (w < 5.0f) {
        w -= 2.5f;
        p = 2.81022636e-08f;
        p = fmaf(p, w, 3.43273939e-07f);
        p = fmaf(p, w, -3.5233877e-06f);
        p = fmaf(p, w, -4.39150654e-06f);
        p = fmaf(p, w, 0.00021858087f);
        p = fmaf(p, w, -0.00125372503f);
        p = fmaf(p, w, -0.00417768164f);
        p = fmaf(p, w, 0.246640727f);
        p = fmaf(p, w, 1.50140941f);
    } else {
        w = sqrtf(w) - 3.0f;
        p = -0.000200214257f;
        p = fmaf(p, w, 0.000100950558f);
        p = fmaf(p, w, 0.00134934322f);
        p = fmaf(p, w, -0.00367342844f);
        p = fmaf(p, w, 0.00573950773f);
        p = fmaf(p, w, -0.0076224613f);
        p = fmaf(p, w, 0.00943887047f);
        p = fmaf(p, w, 1.00167406f);
        p = fmaf(p, w, 2.83297682f);
    }
    double y = (double)(p * xf);
    const double c = 1.1283791670955126;
    for (int it = 0; it < 3; ++it) {
        double err = erf(y) - x;
        y -= err / (c * exp(-y * y));
    }
    return y;
}

struct EpsT { float e[16]; };

static void compute_eps(float* e) {
    const float lo = -0.99999994f;
    for (int i = 0; i < 16; ++i) {
        uint32_t a, b;
        threefry2x32_42(0u, (uint32_t)i, a, b);
        uint32_t bits = a ^ b;
        uint32_t fb = (bits >> 9) | 0x3f800000u;
        float f;
        memcpy(&f, &fb, 4);
        float u = f - 1.0f;
        float v = u * 2.0f + lo;
        if (v < lo) v = lo;
        e[i] = (float)(sqrt(2.0) * erfinv_d((double)v));
    }
}

// ---------------------------------------------------------------------------
// Shuffle-free MFMA chain via K-permutation.
//
// 32x32x16 f16 layouts (verified end-to-end in round 3):
//   C/D: lane (hv=lane>>5, n=lane&31), reg r -> D[row][n], row=(r&3)+8*(r>>2)+4hv
//   A:   lane (hv, m=lane&31), elem j  -> A[m][k=8hv+j]
//   B:   lane (hv, n=lane&31), elem j  -> B[k=8hv+j][n]
//
// Matmul is permutation-invariant over K, so for layers 2/3 we relabel K with
//   sigma(16q + 8hv + j) = 16q + 4hv + 8*(j>>2) + (j&3)
// and load W2/W3 rows through sigma. Then reg r of the previous C/D is exactly
// elem j=r&7 of B-fragment q=r>>3 — NO cross-lane movement (round 3's 72
// ds_bpermute/tile caused 6e7 LDS bank-conflict cycles = ~half the runtime).
//
// W3 is duplicated into output rows 4-7 (A[m][k]=W3[sigma(k)][m&3] for m<8), so
// both wave halves hold the f=0..3 outputs in regs 0-3: hv=0 stores columns
// 0-1, hv=1 stores columns 2-3, and passthrough z-columns are locally held.
// Mask folds into the W1 A-frag (f index = k&3 = j&3, lane-uniform). Biases
// init the accumulators; b3+eps inits the L3 accumulator.
// ---------------------------------------------------------------------------

typedef _Float16 half8 __attribute__((ext_vector_type(8)));
typedef float floatx16 __attribute__((ext_vector_type(16)));

__global__ __launch_bounds__(256) void scm_mfma(
    const float* __restrict__ z,
    const float* __restrict__ W1, const float* __restrict__ b1,
    const float* __restrict__ W2, const float* __restrict__ b2,
    const float* __restrict__ W3, const float* __restrict__ b3,
    const int* __restrict__ mask,
    float* __restrict__ out, EpsT ep, int B)
{
    const int lane = threadIdx.x & 63;
    const int hv   = lane >> 5;          // wave half
    const int n    = lane & 31;          // batch row in tile / m index
    const int wid  = blockIdx.x * (blockDim.x >> 6) + (threadIdx.x >> 6);
    const int nw   = gridDim.x * (blockDim.x >> 6);
    const int T    = B >> 5;             // 32-row tiles

    int mk[16];
#pragma unroll
    for (int t = 0; t < 16; ++t) mk[t] = mask[t];     // uniform -> s_load
    int cond[4];
#pragma unroll
    for (int i = 0; i < 4; ++i) cond[i] = mk[i] | mk[4 + i] | mk[8 + i] | mk[12 + i];

    // ---- weight A-fragments (f16), built once per wave ----
    half8 w1m[4], w2f[2], w3f[2];
#pragma unroll
    for (int j = 0; j < 8; ++j) {
        const int k = hv * 8 + j;                     // k in [0,16), natural
        const float w = W1[k * 32 + n];               // W1^T[m=n][k]
#pragma unroll
        for (int i = 0; i < 4; ++i)                   // mask[f=k&3=j&3][i]
            w1m[i][j] = mk[(j & 3) * 4 + i] ? (_Float16)w : (_Float16)0.f;
    }
#pragma unroll
    for (int q = 0; q < 2; ++q)
#pragma unroll
        for (int j = 0; j < 8; ++j) {
            const int row = 16 * q + 4 * hv + 8 * (j >> 2) + (j & 3);  // sigma(k)
            w2f[q][j] = (_Float16)W2[row * 32 + n];
            w3f[q][j] = (n < 8) ? (_Float16)W3[row * 4 + (n & 3)] : (_Float16)0.f;
        }

    // ---- biases in C/D layout: acc-init ----
    floatx16 b1v, b2v;
#pragma unroll
    for (int r = 0; r < 16; ++r) {
        const int h = (r & 3) + 8 * (r >> 2) + 4 * hv;
        b1v[r] = b1[h];
        b2v[r] = b2[h];
    }
    float c3i[4][4];                                  // b3[f] + eps[i][f] (uniform)
#pragma unroll
    for (int i = 0; i < 4; ++i)
#pragma unroll
        for (int f = 0; f < 4; ++f) c3i[i][f] = b3[f] + ep.e[i * 4 + f];

    // ---- grid-stride tile loop with z prefetch ----
    int t = wid;
    float4 za = make_float4(0.f, 0.f, 0.f, 0.f), zb = za;
    if (t < T) {
        const float4* p = reinterpret_cast<const float4*>(z + ((size_t)t * 32 + n) * 16) + hv * 2;
        za = p[0]; zb = p[1];                         // z[n][hv*8 .. hv*8+7]
    }
    while (t < T) {
        const int tn = t + nw;
        float4 na = make_float4(0.f, 0.f, 0.f, 0.f), nb = na;
        if (tn < T) {
            const float4* p = reinterpret_cast<const float4*>(z + ((size_t)tn * 32 + n) * 16) + hv * 2;
            na = p[0]; nb = p[1];
        }

        const float zf[8] = { za.x, za.y, za.z, za.w, zb.x, zb.y, zb.z, zb.w };
        half8 bz;                                     // Z^T B-frag, k natural
#pragma unroll
        for (int j = 0; j < 8; ++j) bz[j] = (_Float16)zf[j];

        float ov2[8];                                 // this half's 2 columns
#pragma unroll
        for (int i = 0; i < 4; ++i) {
            const int mine = ((i >> 1) == hv);        // columns 2hv, 2hv+1
            if (cond[i]) {
                // L1: K=16, natural order
                floatx16 c1 = b1v;
                c1 = __builtin_amdgcn_mfma_f32_32x32x16_f16(w1m[i], bz, c1, 0, 0, 0);
                // reg r -> B-frag (q=r>>3, j=r&7); relu then cvt
                half8 pa, pb;
#pragma unroll
                for (int j = 0; j < 8; ++j) {
                    pa[j] = (_Float16)fmaxf(c1[j], 0.f);
                    pb[j] = (_Float16)fmaxf(c1[8 + j], 0.f);
                }
                // L2: K=32 via sigma-permuted W2 rows
                floatx16 c2 = b2v;
                c2 = __builtin_amdgcn_mfma_f32_32x32x16_f16(w2f[0], pa, c2, 0, 0, 0);
                c2 = __builtin_amdgcn_mfma_f32_32x32x16_f16(w2f[1], pb, c2, 0, 0, 0);
#pragma unroll
                for (int j = 0; j < 8; ++j) {
                    pa[j] = (_Float16)fmaxf(c2[j], 0.f);
                    pb[j] = (_Float16)fmaxf(c2[8 + j], 0.f);
                }
                // L3: sigma-permuted, W3 duplicated into rows 4-7
                floatx16 c3;
#pragma unroll
                for (int r = 0; r < 16; ++r) c3[r] = (r < 4) ? c3i[i][r] : 0.f;
                c3 = __builtin_amdgcn_mfma_f32_32x32x16_f16(w3f[0], pa, c3, 0, 0, 0);
                c3 = __builtin_amdgcn_mfma_f32_32x32x16_f16(w3f[1], pb, c3, 0, 0, 0);
                if (mine) {
#pragma unroll
                    for (int f = 0; f < 4; ++f) ov2[(i & 1) * 4 + f] = c3[f];
                }
            } else if (mine) {
                // exact f32 passthrough: cols {2hv, 2hv+1} live in zf locally
#pragma unroll
                for (int f = 0; f < 4; ++f) ov2[(i & 1) * 4 + f] = zf[(i & 1) * 4 + f];
            }
        }
        // all 64 lanes store: lane (hv,n) writes out[n][8hv .. 8hv+7]
        float4* op = reinterpret_cast<float4*>(out + ((size_t)t * 32 + n) * 16 + hv * 8);
        op[0] = make_float4(ov2[0], ov2[1], ov2[2], ov2[3]);
        op[1] = make_float4(ov2[4], ov2[5], ov2[6], ov2[7]);

        t = tn; za = na; zb = nb;
    }
}

extern "C" void kernel_launch(void* const* d_in, const int* in_sizes, int n_in,
                              void* d_out, int out_size, void* d_ws, size_t ws_size,
                              hipStream_t stream) {
    const float* z  = (const float*)d_in[0];
    // d_in[1] = z_int (dead code in reference)
    const float* W1 = (const float*)d_in[2];
    const float* b1 = (const float*)d_in[3];
    const float* W2 = (const float*)d_in[4];
    const float* b2 = (const float*)d_in[5];
    const float* W3 = (const float*)d_in[6];
    const float* b3 = (const float*)d_in[7];
    const int* mask = (const int*)d_in[8];
    // d_in[9] = I (dead code in reference)
    float* out = (float*)d_out;

    const int B = in_sizes[0] / 16;

    EpsT ep;
    compute_eps(ep.e);   // pure host math, deterministic, capture-safe

    dim3 grid(2048), block(256);   // 8192 waves, grid-stride over B/32 tiles
    hipLaunchKernelGGL(scm_mfma, grid, block, 0, stream,
                       z, W1, b1, W2, b2, W3, b3, mask, out, ep, B);
}